// Round 17
// baseline (230.384 us; speedup 1.0000x reference)
//
#include <hip/hip_runtime.h>
#include <stdint.h>

#define B_  4
#define S_  2048
#define D_  1024
#define H_  16
#define DK_ 64

typedef __attribute__((ext_vector_type(8)))  short   short8;
typedef __attribute__((ext_vector_type(8)))  unsigned short ushort8;
typedef __attribute__((ext_vector_type(4)))  float   f32x4;
typedef __attribute__((ext_vector_type(16))) float   f32x16;

#define GPTR(p) ((const __attribute__((address_space(1))) void*)(p))
#define SPTR(p) ((__attribute__((address_space(3))) void*)(p))

__device__ inline unsigned short f2bf(float f) {
  uint32_t u = __float_as_uint(f);
  uint32_t r = (u + 0x7fffu + ((u >> 16) & 1u)) >> 16;
  return (unsigned short)r;
}
__device__ inline float bf2f(unsigned short h) {
  return __uint_as_float(((uint32_t)h) << 16);
}
// pack two fp32 -> two bf16 (RNE), single instruction (T12)
__device__ inline uint32_t pkbf(float a, float b) {
  uint32_t r;
  asm("v_cvt_pk_bf16_f32 %0, %1, %2" : "=v"(r) : "v"(a), "v"(b));
  return r;
}
// cross-half exchange: a' = {a.lo32lanes, b.lo32lanes}, b' = {a.hi32lanes, b.hi32lanes}
__device__ inline void pl32(uint32_t& a, uint32_t& b) {
  asm volatile("v_permlane32_swap_b32 %0, %1" : "+v"(a), "+v"(b));
}
__device__ inline short8 mk8(uint32_t a, uint32_t b, uint32_t c, uint32_t d) {
  union { uint32_t u[4]; short8 s; } x;
  x.u[0] = a; x.u[1] = b; x.u[2] = c; x.u[3] = d;
  return x.s;
}

// ---------------- weights fp32 -> bf16 (X is consumed fp32-direct by gemm_qkv) --------
__global__ __launch_bounds__(256) void conv_w4(const float* __restrict__ w0,
                                               const float* __restrict__ w1,
                                               const float* __restrict__ w2,
                                               const float* __restrict__ w3,
                                               unsigned short* __restrict__ dst) {
  const size_t NW = (size_t)D_ * D_;
  const float* src = (blockIdx.z == 0) ? w0 : (blockIdx.z == 1) ? w1
                   : (blockIdx.z == 2) ? w2 : w3;
  unsigned short* d = dst + (size_t)blockIdx.z * NW;
  size_t i = ((size_t)blockIdx.x * blockDim.x + threadIdx.x) * 4;
  if (i < NW) {
    float4 v = *reinterpret_cast<const float4*>(src + i);
    ushort4 o;
    o.x = f2bf(v.x); o.y = f2bf(v.y); o.z = f2bf(v.z); o.w = f2bf(v.w);
    *reinterpret_cast<ushort4*>(d + i) = o;
  }
}

// ---------------- QKV projection GEMM: fp32 X staged via global_load_lds, cvt in-fragment --
// (round-14 version: best measured total. Residual ~6M LDS conflicts on the fp32 tile are
// NOT on the critical path -- round-16 proved a 0-conflict variant runs identically.)
// Tile 128x128xBK32; F = fp32 X (128B rows, swizzle byte^=((row&7)<<4), both-sides rule #21);
// H = bf16 W (64B rows, slot-XOR). F fragment = 2x ds_read_b128 + 4 cvt_pk.
// 2-deep counted-vmcnt pipeline, single barrier per K-step.
#define BM 128
#define BN 128
#define BK 32

// z=0: qp[m][d] = Xq·Wq^T ; z=1: kp[m][d] = Xk·Wk^T ;
// z=2: vtp[d][m] = Wv·Xv^T  (V projection written directly transposed, pitch B*S)
// Block mapping co-locates X-panel-sharing blocks on one XCD (linear id % 8 constant).
__global__ __launch_bounds__(256) void gemm_qkv(const float* __restrict__ Xq,
                                                const float* __restrict__ Xk,
                                                const float* __restrict__ Xv,
                                                const unsigned short* __restrict__ W,
                                                unsigned short* __restrict__ P) {
  const size_t NW = (size_t)D_ * D_;
  const size_t NX = (size_t)B_ * S_ * D_;
  const int z = blockIdx.z;
  const int K = D_;

  const float* F;            // fp32 operand (X), panel rows at f0
  unsigned short* C;
  int N, m0, n0, f0, h0;
  if (z == 2) {
    F = Xv; C = P + 2 * NX; N = B_ * S_;
    n0 = (blockIdx.x & 63) * BN; f0 = n0;    // X-panel (B-side), id%8-grouped
    m0 = (blockIdx.x >> 6) * BM; h0 = m0;    // W rows (A-side) = output rows
  } else {
    F = z ? Xk : Xq; C = P + (size_t)z * NX; N = D_;
    m0 = (blockIdx.x & 63) * BM; f0 = m0;    // X-panel (A-side), id%8-grouped
    n0 = (blockIdx.x >> 6) * BN; h0 = n0;    // W rows (B-side) = output cols
  }
  const unsigned short* Hw = W + (size_t)z * NW;

  __shared__ float          sF[2][BM * BK];   // 2 x 16 KB (fp32 tile, 128B rows)
  __shared__ unsigned short sH[2][BM * BK];   // 2 x  8 KB (bf16 tile,  64B rows)

  const int tid  = threadIdx.x;
  const int lane = tid & 63;
  const int wid  = tid >> 6;
  const int wr   = wid >> 1, wc = wid & 1;
  const int g = lane >> 4, c = lane & 15;

  f32x4 acc[4][4];
#pragma unroll
  for (int m = 0; m < 4; ++m)
#pragma unroll
    for (int n = 0; n < 4; ++n) acc[m][n] = (f32x4){0.f, 0.f, 0.f, 0.f};

  // stage one K-step: F tile (16 KB, 4 loads/wave) + H tile (8 KB, 2 loads/wave)
  auto stage = [&](int kt_, int bs) {
    const int k0 = kt_ * BK;
#pragma unroll
    for (int i = 0; i < 4; ++i) {
      const int base_ob = i * 4096 + wid * 1024;
      const int ob  = base_ob + lane * 16;
      const int row = ob >> 7;                            // 128 B per fp32 row
      const int scb = (ob & 127) ^ ((row & 7) << 4);      // inverse-swizzled source (bytes)
      const float* gf = F + (size_t)(f0 + row) * K + k0 + (scb >> 2);
      __builtin_amdgcn_global_load_lds(GPTR(gf), SPTR(&sF[bs][base_ob >> 2]), 16, 0, 0);
    }
#pragma unroll
    for (int i = 0; i < 2; ++i) {
      const int base_ob = i * 4096 + wid * 1024;
      const int ob  = base_ob + lane * 16;
      const int row = ob >> 6;                            // 64 B per bf16 row
      const int scb = (ob & 63) ^ (((ob >> 7) & 3) << 4); // inverse-swizzled source
      const unsigned short* gh = Hw + (size_t)(h0 + row) * K + k0 + (scb >> 1);
      __builtin_amdgcn_global_load_lds(GPTR(gh), SPTR(&sH[bs][base_ob >> 1]), 16, 0, 0);
    }
  };

  // F fragment: row r, k-chunk g -> 8 fp32 (two swizzled b128) -> short8 via cvt_pk
  auto loadF = [&](const float* Fb, int r) -> short8 {
    const int b0 = r * 128 + (((g * 32)      ) ^ ((r & 7) << 4));
    const int b1 = r * 128 + (((g * 32) + 16 ) ^ ((r & 7) << 4));
    f32x4 x0 = *reinterpret_cast<const f32x4*>(
        reinterpret_cast<const char*>(Fb) + b0);
    f32x4 x1 = *reinterpret_cast<const f32x4*>(
        reinterpret_cast<const char*>(Fb) + b1);
    return mk8(pkbf(x0[0], x0[1]), pkbf(x0[2], x0[3]),
               pkbf(x1[0], x1[1]), pkbf(x1[2], x1[3]));
  };
  auto loadH = [&](const unsigned short* Hb, int r) -> short8 {
    return *reinterpret_cast<const short8*>(
        &Hb[r * BK + ((g ^ ((r >> 1) & 3)) << 3)]);
  };

  const int nkt = K / BK;   // 32
  stage(0, 0);
  for (int kt = 0; kt < nkt; ++kt) {
    const int cur = kt & 1;
    __builtin_amdgcn_s_barrier();
    __builtin_amdgcn_sched_barrier(0);
    if (kt + 1 < nkt) {
      stage(kt + 1, cur ^ 1);                           // 12 outstanding
      asm volatile("s_waitcnt vmcnt(6)" ::: "memory");  // tile kt's 6 loads done
    } else {
      asm volatile("s_waitcnt vmcnt(0)" ::: "memory");
    }
    __builtin_amdgcn_sched_barrier(0);

    short8 af[4], bf[4];
    if (z == 2) {
#pragma unroll
      for (int m = 0; m < 4; ++m) af[m] = loadH(&sH[cur][0], wr * 64 + m * 16 + c);
#pragma unroll
      for (int n = 0; n < 4; ++n) bf[n] = loadF(&sF[cur][0], wc * 64 + n * 16 + c);
    } else {
#pragma unroll
      for (int m = 0; m < 4; ++m) af[m] = loadF(&sF[cur][0], wr * 64 + m * 16 + c);
#pragma unroll
      for (int n = 0; n < 4; ++n) bf[n] = loadH(&sH[cur][0], wc * 64 + n * 16 + c);
    }
    __builtin_amdgcn_s_setprio(1);
#pragma unroll
    for (int m = 0; m < 4; ++m)
#pragma unroll
      for (int n = 0; n < 4; ++n)
        acc[m][n] = __builtin_amdgcn_mfma_f32_16x16x32_bf16(af[m], bf[n], acc[m][n], 0, 0, 0);
    __builtin_amdgcn_s_setprio(0);
  }

#pragma unroll
  for (int m = 0; m < 4; ++m)
#pragma unroll
    for (int n = 0; n < 4; ++n)
#pragma unroll
      for (int r = 0; r < 4; ++r) {
        const int row = m0 + wr * 64 + m * 16 + 4 * g + r;
        const int col = n0 + wc * 64 + n * 16 + c;
        C[(size_t)row * N + col] = f2bf(acc[m][n][r]);
      }
}

// ---------------- output projection GEMM (bf16 in, fp32 out; 2-deep single-barrier) ------
__global__ __launch_bounds__(256, 5) void gemm_out(const unsigned short* __restrict__ A,
                                                   const unsigned short* __restrict__ Bm,
                                                   float* __restrict__ C,
                                                   int M, int N, int K) {
  __shared__ unsigned short sA[2][BM * BK];
  __shared__ unsigned short sB[2][BN * BK];

  const int tid  = threadIdx.x;
  const int lane = tid & 63;
  const int wid  = tid >> 6;
  const int wr   = wid >> 1, wc = wid & 1;
  const int g = lane >> 4, c = lane & 15;

  const int m0 = blockIdx.x * BM;
  const int n0 = blockIdx.y * BN;

  f32x4 acc[4][4];
#pragma unroll
  for (int m = 0; m < 4; ++m)
#pragma unroll
    for (int n = 0; n < 4; ++n) acc[m][n] = (f32x4){0.f, 0.f, 0.f, 0.f};

  auto stage = [&](int kt_, int bs) {
    const int k0 = kt_ * BK;
#pragma unroll
    for (int i = 0; i < 2; ++i) {
      const int base_ob = i * 4096 + wid * 1024;
      const int ob  = base_ob + lane * 16;
      const int row = ob >> 6;
      const int scb = (ob & 63) ^ (((ob >> 7) & 3) << 4);
      const unsigned short* ga = A  + (size_t)(m0 + row) * K + k0 + (scb >> 1);
      const unsigned short* gb = Bm + (size_t)(n0 + row) * K + k0 + (scb >> 1);
      __builtin_amdgcn_global_load_lds(GPTR(ga), SPTR(&sA[bs][base_ob >> 1]), 16, 0, 0);
      __builtin_amdgcn_global_load_lds(GPTR(gb), SPTR(&sB[bs][base_ob >> 1]), 16, 0, 0);
    }
  };

  const int nkt = K / BK;
  stage(0, 0);
  for (int kt = 0; kt < nkt; ++kt) {
    const int cur = kt & 1;
    __builtin_amdgcn_s_barrier();
    __builtin_amdgcn_sched_barrier(0);
    if (kt + 1 < nkt) {
      stage(kt + 1, cur ^ 1);
      asm volatile("s_waitcnt vmcnt(4)" ::: "memory");
    } else {
      asm volatile("s_waitcnt vmcnt(0)" ::: "memory");
    }
    __builtin_amdgcn_sched_barrier(0);

    short8 af[4], bf[4];
#pragma unroll
    for (int m = 0; m < 4; ++m) {
      const int ra = wr * 64 + m * 16 + c;
      af[m] = *reinterpret_cast<const short8*>(
          &sA[cur][ra * BK + ((g ^ ((ra >> 1) & 3)) << 3)]);
    }
#pragma unroll
    for (int n = 0; n < 4; ++n) {
      const int rb = wc * 64 + n * 16 + c;
      bf[n] = *reinterpret_cast<const short8*>(
          &sB[cur][rb * BK + ((g ^ ((rb >> 1) & 3)) << 3)]);
    }
    __builtin_amdgcn_s_setprio(1);
#pragma unroll
    for (int m = 0; m < 4; ++m)
#pragma unroll
      for (int n = 0; n < 4; ++n)
        acc[m][n] = __builtin_amdgcn_mfma_f32_16x16x32_bf16(af[m], bf[n], acc[m][n], 0, 0, 0);
    __builtin_amdgcn_s_setprio(0);
  }

#pragma unroll
  for (int m = 0; m < 4; ++m)
#pragma unroll
    for (int n = 0; n < 4; ++n)
#pragma unroll
      for (int r = 0; r < 4; ++r) {
        const int row = m0 + wr * 64 + m * 16 + 4 * g + r;
        const int col = n0 + wc * 64 + n * 16 + c;
        C[(size_t)row * N + col] = acc[m][n][r];
      }
}

// ---------------- causal flash attention (bf16; K in [B,S,D], V^T in [D, B*S]) --------
// Grid (64 bh, 16 qt): linear id % 8 = bh % 8 -> same-head blocks share an XCD L2.
// One qtile per block, longest first. 5 blocks/CU (32KB LDS, VGPR<=102). Single barrier
// per kv-tile; one extra barrier before the epilogue's LDS reuse. Swapped QK^T,
// in-register softmax, T12 repack, T13 defer-max.
__global__ __launch_bounds__(256, 5) void attn_fwd(const unsigned short* __restrict__ qp,
                                                   const unsigned short* __restrict__ kp,
                                                   const unsigned short* __restrict__ vtp,
                                                   unsigned short* __restrict__ attn) {
  const int bh = blockIdx.x;               // head-major for XCD locality
  const int qtile = 15 - (int)blockIdx.y;  // longest blocks dispatch first
  const int b = bh >> 4, h = bh & 15;

  // 32KB flat LDS: [0,8192) = K dbuf, [8192,16384) = V^T dbuf (shorts). Epilogue reuses it.
  __shared__ unsigned short smem[4 * 64 * 64];

  const int tid  = threadIdx.x;
  const int lane = tid & 63;
  const int wid  = tid >> 6;
  const int hi   = lane >> 5;       // half-wave
  const int lo5  = lane & 31;       // this lane's q (and d) row index

  const size_t headoff  = (size_t)b * S_ * D_ + (size_t)h * DK_;
  const size_t vheadoff = (size_t)(h * DK_) * (size_t)(B_ * S_) + (size_t)b * S_;

  const int xk = (lo5 & 7) << 4;    // read-side XOR (row&7 == lo5&7 for rows lo5, lo5+32)

  // stage K tile ([kv][dk], 8KB) + V^T tile ([d][kv], 8KB) into dbuf slot bs.
  auto stage = [&](int kt_, int bs) {
#pragma unroll
    for (int i = 0; i < 2; ++i) {
      const int base_ob = i * 4096 + wid * 1024;
      const int ob  = base_ob + lane * 16;
      const int row = ob >> 7;                          // 128B per row
      const int scb = (ob & 127) ^ ((row & 7) << 4);    // swizzled source column (bytes)
      const unsigned short* gk = &kp[headoff + (size_t)(kt_ * 64 + row) * D_ + (scb >> 1)];
      const unsigned short* gv = &vtp[vheadoff + (size_t)row * (B_ * S_) + kt_ * 64 + (scb >> 1)];
      __builtin_amdgcn_global_load_lds(GPTR(gk), SPTR(&smem[bs * 4096 + (base_ob >> 1)]), 16, 0, 0);
      __builtin_amdgcn_global_load_lds(GPTR(gv), SPTR(&smem[8192 + bs * 4096 + (base_ob >> 1)]), 16, 0, 0);
    }
  };

  const int qw = qtile * 128 + wid * 32;   // wave's first q row
  const int qg = qw + lo5;                 // lane's q row

  // Q B-fragments: aq[t] holds Q[qg][dk=16t+8hi .. +8], pre-scaled by 1/8 (exact)
  short8 aq[4];
#pragma unroll
  for (int t = 0; t < 4; ++t) {
    ushort8 raw = *reinterpret_cast<const ushort8*>(
        &qp[headoff + (size_t)qg * D_ + t * 16 + hi * 8]);
    short8 sv;
#pragma unroll
    for (int j = 0; j < 8; ++j) sv[j] = (short)f2bf(bf2f(raw[j]) * 0.125f);
    aq[t] = sv;
  }

  float mrun = -3.0e38f, lrun = 0.f;
  f32x16 oa0, oa1;   // O^T accum: lane holds O[qg][d = d32*32 + (reg&3)+8*(reg>>2)+4*hi]
#pragma unroll
  for (int r = 0; r < 16; ++r) { oa0[r] = 0.f; oa1[r] = 0.f; }

  const int nkv = 2 * (qtile + 1);
  stage(0, 0);  // prologue: 4 loads in flight

  for (int kt = 0; kt < nkv; ++kt) {
    const int cur = kt & 1;
    __builtin_amdgcn_s_barrier();
    __builtin_amdgcn_sched_barrier(0);
    if (kt < nkv - 1) {
      stage(kt + 1, cur ^ 1);                           // issue next tile -> 8 outstanding
      asm volatile("s_waitcnt vmcnt(4)" ::: "memory");  // tile kt's 4 loads done
    } else {
      asm volatile("s_waitcnt vmcnt(0)" ::: "memory");  // last tile: drain
    }
    __builtin_amdgcn_sched_barrier(0);

    const int kv0 = kt * 64;
    if (kv0 <= qw + 31) {   // not fully masked for this wave
      const unsigned short* Kb = &smem[cur * 4096];
      const unsigned short* Vb = &smem[8192 + cur * 4096];

      // ---- S^T = K · Q^T : st{0,1}[reg] = S[kv0 + s*32 + (reg&3)+8*(reg>>2)+4*hi][qg]
      f32x16 st0, st1;
#pragma unroll
      for (int r = 0; r < 16; ++r) { st0[r] = 0.f; st1[r] = 0.f; }
      __builtin_amdgcn_s_setprio(1);
#pragma unroll
      for (int t = 0; t < 4; ++t) {
        const int off = ((32 * t + 16 * hi) ^ xk) >> 1;   // shorts
        short8 k0 = *reinterpret_cast<const short8*>(&Kb[lo5 * 64 + off]);
        short8 k1 = *reinterpret_cast<const short8*>(&Kb[(32 + lo5) * 64 + off]);
        st0 = __builtin_amdgcn_mfma_f32_32x32x16_bf16(k0, aq[t], st0, 0, 0, 0);
        st1 = __builtin_amdgcn_mfma_f32_32x32x16_bf16(k1, aq[t], st1, 0, 0, 0);
      }
      __builtin_amdgcn_s_setprio(0);

      // ---- causal mask (only when tile overlaps the diagonal for this wave)
      if (kv0 + 63 > qw) {
#pragma unroll
        for (int r = 0; r < 16; ++r) {
          const int kvl = kv0 + (r & 3) + 8 * (r >> 2) + 4 * hi;
          if (kvl > qg)      st0[r] = -3.0e38f;
          if (kvl + 32 > qg) st1[r] = -3.0e38f;
        }
      }

      // ---- row max (in-lane tree + one cross-half exchange) with T13 defer-max
      float tm = fmaxf(st0[0], st1[0]);
#pragma unroll
      for (int r = 1; r < 16; ++r) tm = fmaxf(tm, fmaxf(st0[r], st1[r]));
      tm = fmaxf(tm, __shfl_xor(tm, 32));
      const bool grow = !__all(tm <= mrun + 8.0f);   // wave-uniform
      float alpha = 1.0f;
      if (grow) {
        const float newm = fmaxf(mrun, tm);
        alpha = __expf(mrun - newm);
        mrun = newm;
      }

      // ---- exp + sum + pack subtile 0 (cvt_pk + permlane32_swap, no hi branch)
      float ls = 0.f;
#pragma unroll
      for (int r = 0; r < 16; ++r) { st0[r] = __expf(st0[r] - mrun); ls += st0[r]; }
      uint32_t a0 = pkbf(st0[0],  st0[1]),  a1 = pkbf(st0[2],  st0[3]);
      uint32_t b0 = pkbf(st0[4],  st0[5]),  b1 = pkbf(st0[6],  st0[7]);
      uint32_t c0 = pkbf(st0[8],  st0[9]),  c1 = pkbf(st0[10], st0[11]);
      uint32_t d0 = pkbf(st0[12], st0[13]), d1 = pkbf(st0[14], st0[15]);
      pl32(a0, b0); pl32(a1, b1);
      pl32(c0, d0); pl32(c1, d1);
      short8 pf0 = mk8(a0, a1, b0, b1);   // kv block 0..15
      short8 pf1 = mk8(c0, c1, d0, d1);   // kv block 16..31

      // ---- exp + sum + pack subtile 1
#pragma unroll
      for (int r = 0; r < 16; ++r) { st1[r] = __expf(st1[r] - mrun); ls += st1[r]; }
      uint32_t e0 = pkbf(st1[0],  st1[1]),  e1 = pkbf(st1[2],  st1[3]);
      uint32_t f0 = pkbf(st1[4],  st1[5]),  f1 = pkbf(st1[6],  st1[7]);
      uint32_t g0 = pkbf(st1[8],  st1[9]),  g1 = pkbf(st1[10], st1[11]);
      uint32_t h0 = pkbf(st1[12], st1[13]), h1 = pkbf(st1[14], st1[15]);
      pl32(e0, f0); pl32(e1, f1);
      pl32(g0, h0); pl32(g1, h1);
      short8 pf2 = mk8(e0, e1, f0, f1);   // kv block 32..47
      short8 pf3 = mk8(g0, g1, h0, h1);   // kv block 48..63

      // ---- running sum + (conditional) O rescale
      ls += __shfl_xor(ls, 32);
      if (grow) {
        lrun = lrun * alpha + ls;
#pragma unroll
        for (int r = 0; r < 16; ++r) { oa0[r] *= alpha; oa1[r] *= alpha; }
      } else {
        lrun += ls;
      }

      // ---- O^T += V^T · P^T : A = V^T frag (rows d), B = P frag
      __builtin_amdgcn_s_setprio(1);
#pragma unroll
      for (int c4 = 0; c4 < 4; ++c4) {
        const int off = ((32 * c4 + 16 * hi) ^ xk) >> 1;
        short8 v0 = *reinterpret_cast<const short8*>(&Vb[lo5 * 64 + off]);
        short8 v1 = *reinterpret_cast<const short8*>(&Vb[(32 + lo5) * 64 + off]);
        const short8 pf = (c4 == 0) ? pf0 : (c4 == 1) ? pf1 : (c4 == 2) ? pf2 : pf3;
        oa0 = __builtin_amdgcn_mfma_f32_32x32x16_bf16(v0, pf, oa0, 0, 0, 0);
        oa1 = __builtin_amdgcn_mfma_f32_32x32x16_bf16(v1, pf, oa1, 0, 0, 0);
      }
      __builtin_amdgcn_s_setprio(0);
    }
  }

  // all waves' final-tile LDS reads consumed before epilogue reuses smem
  __builtin_amdgcn_s_barrier();
  __builtin_amdgcn_sched_barrier(0);

  // ---- epilogue: O^T -> LDS (per-wave region, pitch 72) -> coalesced global write
  {
    unsigned short* sO = &smem[wid * (32 * 72)];
    const float inv = 1.0f / lrun;
#pragma unroll
    for (int r = 0; r < 16; ++r) {
      const int dl = (r & 3) + 8 * (r >> 2) + 4 * hi;
      sO[lo5 * 72 + dl]      = f2bf(oa0[r] * inv);
      sO[lo5 * 72 + 32 + dl] = f2bf(oa1[r] * inv);
    }
    asm volatile("s_waitcnt lgkmcnt(0)" ::: "memory");  // own-wave LDS writes visible
    const int row = lane >> 1, h2 = lane & 1;
    const unsigned short* src = &smem[wid * (32 * 72) + row * 72 + h2 * 32];
    unsigned short* dst = &attn[headoff + (size_t)(qtile * 128 + wid * 32 + row) * D_ + h2 * 32];
#pragma unroll
    for (int j = 0; j < 4; ++j)
      *reinterpret_cast<short8*>(dst + 8 * j) = *reinterpret_cast<const short8*>(src + 8 * j);
  }
}

// ---------------- launcher ----------------
extern "C" void kernel_launch(void* const* d_in, const int* in_sizes, int n_in,
                              void* d_out, int out_size, void* d_ws, size_t ws_size,
                              hipStream_t stream) {
  const float* Q  = (const float*)d_in[0];
  const float* K  = (const float*)d_in[1];
  const float* V  = (const float*)d_in[2];
  // d_in[3] = mask: known causal tril, applied analytically
  const float* Wq = (const float*)d_in[4];
  const float* Wk = (const float*)d_in[5];
  const float* Wv = (const float*)d_in[6];
  const float* Wo = (const float*)d_in[7];
  float* out = (float*)d_out;

  const size_t NX = (size_t)B_ * S_ * D_;  // 8,388,608
  const size_t NW = (size_t)D_ * D_;       // 1,048,576

  unsigned short* ws = (unsigned short*)d_ws;
  unsigned short* Wb = ws;                 // 4*NW
  unsigned short* Pj = Wb + 4 * NW;        // 3*NX  (qp, kp, vtp[D][B*S])
  unsigned short* At = Pj + 3 * NX;        // NX

  const int M = B_ * S_;  // 8192
  dim3 blk(256);
  dim3 gridConvW((unsigned)(NW / 4 / 256), 1, 4);
  dim3 gridQKV(512, 1, 3);
  dim3 gridOut(M / BM, D_ / BN);           // m-major: same-panel blocks share an XCD
  dim3 gridAttn(B_ * H_, 16);              // head-major: same-head blocks share an XCD

  // weights -> bf16 (X is read fp32-direct by gemm_qkv)
  conv_w4<<<gridConvW, blk, 0, stream>>>(Wq, Wk, Wv, Wo, Wb);
  // QKV projection (fp32 X staged + converted in-kernel; V written directly transposed)
  gemm_qkv<<<gridQKV, blk, 0, stream>>>(Q, K, V, Wb, Pj);
  // attention (V^T layout [D][B*S])
  attn_fwd<<<gridAttn, blk, 0, stream>>>(Pj, Pj + NX, Pj + 2 * NX, At);
  // output projection (fp32 out)
  gemm_out<<<gridOut, blk, 0, stream>>>(At, Wb + 3 * NW, out, M, D_, D_);
}

// Round 18
// 173.062 us; speedup vs baseline: 1.3312x; 1.3312x over previous
//
#include <hip/hip_runtime.h>
#include <stdint.h>

#define B_  4
#define S_  2048
#define D_  1024
#define H_  16
#define DK_ 64

typedef __attribute__((ext_vector_type(8)))  short   short8;
typedef __attribute__((ext_vector_type(8)))  unsigned short ushort8;
typedef __attribute__((ext_vector_type(4)))  float   f32x4;
typedef __attribute__((ext_vector_type(16))) float   f32x16;

#define GPTR(p) ((const __attribute__((address_space(1))) void*)(p))
#define SPTR(p) ((__attribute__((address_space(3))) void*)(p))

__device__ inline unsigned short f2bf(float f) {
  uint32_t u = __float_as_uint(f);
  uint32_t r = (u + 0x7fffu + ((u >> 16) & 1u)) >> 16;
  return (unsigned short)r;
}
__device__ inline float bf2f(unsigned short h) {
  return __uint_as_float(((uint32_t)h) << 16);
}
// pack two fp32 -> two bf16 (RNE), single instruction (T12)
__device__ inline uint32_t pkbf(float a, float b) {
  uint32_t r;
  asm("v_cvt_pk_bf16_f32 %0, %1, %2" : "=v"(r) : "v"(a), "v"(b));
  return r;
}
// cross-half exchange: a' = {a.lo32lanes, b.lo32lanes}, b' = {a.hi32lanes, b.hi32lanes}
__device__ inline void pl32(uint32_t& a, uint32_t& b) {
  asm volatile("v_permlane32_swap_b32 %0, %1" : "+v"(a), "+v"(b));
}
__device__ inline short8 mk8(uint32_t a, uint32_t b, uint32_t c, uint32_t d) {
  union { uint32_t u[4]; short8 s; } x;
  x.u[0] = a; x.u[1] = b; x.u[2] = c; x.u[3] = d;
  return x.s;
}

// ---------------- weights fp32 -> bf16 (X is consumed fp32-direct by gemm_qkv) --------
__global__ __launch_bounds__(256) void conv_w4(const float* __restrict__ w0,
                                               const float* __restrict__ w1,
                                               const float* __restrict__ w2,
                                               const float* __restrict__ w3,
                                               unsigned short* __restrict__ dst) {
  const size_t NW = (size_t)D_ * D_;
  const float* src = (blockIdx.z == 0) ? w0 : (blockIdx.z == 1) ? w1
                   : (blockIdx.z == 2) ? w2 : w3;
  unsigned short* d = dst + (size_t)blockIdx.z * NW;
  size_t i = ((size_t)blockIdx.x * blockDim.x + threadIdx.x) * 4;
  if (i < NW) {
    float4 v = *reinterpret_cast<const float4*>(src + i);
    ushort4 o;
    o.x = f2bf(v.x); o.y = f2bf(v.y); o.z = f2bf(v.z); o.w = f2bf(v.w);
    *reinterpret_cast<ushort4*>(d + i) = o;
  }
}

// ---------------- QKV projection GEMM: fp32 X staged via global_load_lds, cvt in-fragment --
// (round-14 configuration: best measured total 174.1 us. Residual ~6M LDS conflicts on
// the fp32 tile are NOT on the critical path -- a 0-conflict variant ran identically.)
// Tile 128x128xBK32; F = fp32 X (128B rows, swizzle byte^=((row&7)<<4), both-sides rule #21);
// H = bf16 W (64B rows, slot-XOR). F fragment = 2x ds_read_b128 + 4 cvt_pk.
// 2-deep counted-vmcnt pipeline, single barrier per K-step.
#define BM 128
#define BN 128
#define BK 32

// z=0: qp[m][d] = Xq·Wq^T ; z=1: kp[m][d] = Xk·Wk^T ;
// z=2: vtp[d][m] = Wv·Xv^T  (V projection written directly transposed, pitch B*S)
// Block mapping co-locates X-panel-sharing blocks on one XCD (linear id % 8 constant).
__global__ __launch_bounds__(256) void gemm_qkv(const float* __restrict__ Xq,
                                                const float* __restrict__ Xk,
                                                const float* __restrict__ Xv,
                                                const unsigned short* __restrict__ W,
                                                unsigned short* __restrict__ P) {
  const size_t NW = (size_t)D_ * D_;
  const size_t NX = (size_t)B_ * S_ * D_;
  const int z = blockIdx.z;
  const int K = D_;

  const float* F;            // fp32 operand (X), panel rows at f0
  unsigned short* C;
  int N, m0, n0, f0, h0;
  if (z == 2) {
    F = Xv; C = P + 2 * NX; N = B_ * S_;
    n0 = (blockIdx.x & 63) * BN; f0 = n0;    // X-panel (B-side), id%8-grouped
    m0 = (blockIdx.x >> 6) * BM; h0 = m0;    // W rows (A-side) = output rows
  } else {
    F = z ? Xk : Xq; C = P + (size_t)z * NX; N = D_;
    m0 = (blockIdx.x & 63) * BM; f0 = m0;    // X-panel (A-side), id%8-grouped
    n0 = (blockIdx.x >> 6) * BN; h0 = n0;    // W rows (B-side) = output cols
  }
  const unsigned short* Hw = W + (size_t)z * NW;

  __shared__ float          sF[2][BM * BK];   // 2 x 16 KB (fp32 tile, 128B rows)
  __shared__ unsigned short sH[2][BM * BK];   // 2 x  8 KB (bf16 tile,  64B rows)

  const int tid  = threadIdx.x;
  const int lane = tid & 63;
  const int wid  = tid >> 6;
  const int wr   = wid >> 1, wc = wid & 1;
  const int g = lane >> 4, c = lane & 15;

  f32x4 acc[4][4];
#pragma unroll
  for (int m = 0; m < 4; ++m)
#pragma unroll
    for (int n = 0; n < 4; ++n) acc[m][n] = (f32x4){0.f, 0.f, 0.f, 0.f};

  // stage one K-step: F tile (16 KB, 4 loads/wave) + H tile (8 KB, 2 loads/wave)
  auto stage = [&](int kt_, int bs) {
    const int k0 = kt_ * BK;
#pragma unroll
    for (int i = 0; i < 4; ++i) {
      const int base_ob = i * 4096 + wid * 1024;
      const int ob  = base_ob + lane * 16;
      const int row = ob >> 7;                            // 128 B per fp32 row
      const int scb = (ob & 127) ^ ((row & 7) << 4);      // inverse-swizzled source (bytes)
      const float* gf = F + (size_t)(f0 + row) * K + k0 + (scb >> 2);
      __builtin_amdgcn_global_load_lds(GPTR(gf), SPTR(&sF[bs][base_ob >> 2]), 16, 0, 0);
    }
#pragma unroll
    for (int i = 0; i < 2; ++i) {
      const int base_ob = i * 4096 + wid * 1024;
      const int ob  = base_ob + lane * 16;
      const int row = ob >> 6;                            // 64 B per bf16 row
      const int scb = (ob & 63) ^ (((ob >> 7) & 3) << 4); // inverse-swizzled source
      const unsigned short* gh = Hw + (size_t)(h0 + row) * K + k0 + (scb >> 1);
      __builtin_amdgcn_global_load_lds(GPTR(gh), SPTR(&sH[bs][base_ob >> 1]), 16, 0, 0);
    }
  };

  // F fragment: row r, k-chunk g -> 8 fp32 (two swizzled b128) -> short8 via cvt_pk
  auto loadF = [&](const float* Fb, int r) -> short8 {
    const int b0 = r * 128 + (((g * 32)      ) ^ ((r & 7) << 4));
    const int b1 = r * 128 + (((g * 32) + 16 ) ^ ((r & 7) << 4));
    f32x4 x0 = *reinterpret_cast<const f32x4*>(
        reinterpret_cast<const char*>(Fb) + b0);
    f32x4 x1 = *reinterpret_cast<const f32x4*>(
        reinterpret_cast<const char*>(Fb) + b1);
    return mk8(pkbf(x0[0], x0[1]), pkbf(x0[2], x0[3]),
               pkbf(x1[0], x1[1]), pkbf(x1[2], x1[3]));
  };
  auto loadH = [&](const unsigned short* Hb, int r) -> short8 {
    return *reinterpret_cast<const short8*>(
        &Hb[r * BK + ((g ^ ((r >> 1) & 3)) << 3)]);
  };

  const int nkt = K / BK;   // 32
  stage(0, 0);
  for (int kt = 0; kt < nkt; ++kt) {
    const int cur = kt & 1;
    __builtin_amdgcn_s_barrier();
    __builtin_amdgcn_sched_barrier(0);
    if (kt + 1 < nkt) {
      stage(kt + 1, cur ^ 1);                           // 12 outstanding
      asm volatile("s_waitcnt vmcnt(6)" ::: "memory");  // tile kt's 6 loads done
    } else {
      asm volatile("s_waitcnt vmcnt(0)" ::: "memory");
    }
    __builtin_amdgcn_sched_barrier(0);

    short8 af[4], bf[4];
    if (z == 2) {
#pragma unroll
      for (int m = 0; m < 4; ++m) af[m] = loadH(&sH[cur][0], wr * 64 + m * 16 + c);
#pragma unroll
      for (int n = 0; n < 4; ++n) bf[n] = loadF(&sF[cur][0], wc * 64 + n * 16 + c);
    } else {
#pragma unroll
      for (int m = 0; m < 4; ++m) af[m] = loadF(&sF[cur][0], wr * 64 + m * 16 + c);
#pragma unroll
      for (int n = 0; n < 4; ++n) bf[n] = loadH(&sH[cur][0], wc * 64 + n * 16 + c);
    }
    __builtin_amdgcn_s_setprio(1);
#pragma unroll
    for (int m = 0; m < 4; ++m)
#pragma unroll
      for (int n = 0; n < 4; ++n)
        acc[m][n] = __builtin_amdgcn_mfma_f32_16x16x32_bf16(af[m], bf[n], acc[m][n], 0, 0, 0);
    __builtin_amdgcn_s_setprio(0);
  }

#pragma unroll
  for (int m = 0; m < 4; ++m)
#pragma unroll
    for (int n = 0; n < 4; ++n)
#pragma unroll
      for (int r = 0; r < 4; ++r) {
        const int row = m0 + wr * 64 + m * 16 + 4 * g + r;
        const int col = n0 + wc * 64 + n * 16 + c;
        C[(size_t)row * N + col] = f2bf(acc[m][n][r]);
      }
}

// ---------------- output projection GEMM (bf16 in, fp32 out; 2-deep single-barrier) ------
__global__ __launch_bounds__(256) void gemm_out(const unsigned short* __restrict__ A,
                                                const unsigned short* __restrict__ Bm,
                                                float* __restrict__ C,
                                                int M, int N, int K) {
  __shared__ unsigned short sA[2][BM * BK];
  __shared__ unsigned short sB[2][BN * BK];

  const int tid  = threadIdx.x;
  const int lane = tid & 63;
  const int wid  = tid >> 6;
  const int wr   = wid >> 1, wc = wid & 1;
  const int g = lane >> 4, c = lane & 15;

  const int m0 = blockIdx.x * BM;
  const int n0 = blockIdx.y * BN;

  f32x4 acc[4][4];
#pragma unroll
  for (int m = 0; m < 4; ++m)
#pragma unroll
    for (int n = 0; n < 4; ++n) acc[m][n] = (f32x4){0.f, 0.f, 0.f, 0.f};

  auto stage = [&](int kt_, int bs) {
    const int k0 = kt_ * BK;
#pragma unroll
    for (int i = 0; i < 2; ++i) {
      const int base_ob = i * 4096 + wid * 1024;
      const int ob  = base_ob + lane * 16;
      const int row = ob >> 6;
      const int scb = (ob & 63) ^ (((ob >> 7) & 3) << 4);
      const unsigned short* ga = A  + (size_t)(m0 + row) * K + k0 + (scb >> 1);
      const unsigned short* gb = Bm + (size_t)(n0 + row) * K + k0 + (scb >> 1);
      __builtin_amdgcn_global_load_lds(GPTR(ga), SPTR(&sA[bs][base_ob >> 1]), 16, 0, 0);
      __builtin_amdgcn_global_load_lds(GPTR(gb), SPTR(&sB[bs][base_ob >> 1]), 16, 0, 0);
    }
  };

  const int nkt = K / BK;
  stage(0, 0);
  for (int kt = 0; kt < nkt; ++kt) {
    const int cur = kt & 1;
    __builtin_amdgcn_s_barrier();
    __builtin_amdgcn_sched_barrier(0);
    if (kt + 1 < nkt) {
      stage(kt + 1, cur ^ 1);
      asm volatile("s_waitcnt vmcnt(4)" ::: "memory");
    } else {
      asm volatile("s_waitcnt vmcnt(0)" ::: "memory");
    }
    __builtin_amdgcn_sched_barrier(0);

    short8 af[4], bf[4];
#pragma unroll
    for (int m = 0; m < 4; ++m) {
      const int ra = wr * 64 + m * 16 + c;
      af[m] = *reinterpret_cast<const short8*>(
          &sA[cur][ra * BK + ((g ^ ((ra >> 1) & 3)) << 3)]);
    }
#pragma unroll
    for (int n = 0; n < 4; ++n) {
      const int rb = wc * 64 + n * 16 + c;
      bf[n] = *reinterpret_cast<const short8*>(
          &sB[cur][rb * BK + ((g ^ ((rb >> 1) & 3)) << 3)]);
    }
    __builtin_amdgcn_s_setprio(1);
#pragma unroll
    for (int m = 0; m < 4; ++m)
#pragma unroll
      for (int n = 0; n < 4; ++n)
        acc[m][n] = __builtin_amdgcn_mfma_f32_16x16x32_bf16(af[m], bf[n], acc[m][n], 0, 0, 0);
    __builtin_amdgcn_s_setprio(0);
  }

#pragma unroll
  for (int m = 0; m < 4; ++m)
#pragma unroll
    for (int n = 0; n < 4; ++n)
#pragma unroll
      for (int r = 0; r < 4; ++r) {
        const int row = m0 + wr * 64 + m * 16 + 4 * g + r;
        const int col = n0 + wc * 64 + n * 16 + c;
        C[(size_t)row * N + col] = acc[m][n][r];
      }
}

// ---------------- causal flash attention (bf16; K in [B,S,D], V^T in [D, B*S]) --------
// Grid (64 bh, 16 qt): linear id % 8 = bh % 8 -> same-head blocks share an XCD L2.
// One qtile per block, longest first. Single barrier per kv-tile; one extra barrier
// before the epilogue's LDS reuse. Swapped QK^T, in-register softmax, T12 repack,
// T13 defer-max.
__global__ __launch_bounds__(256, 4) void attn_fwd(const unsigned short* __restrict__ qp,
                                                   const unsigned short* __restrict__ kp,
                                                   const unsigned short* __restrict__ vtp,
                                                   unsigned short* __restrict__ attn) {
  const int bh = blockIdx.x;               // head-major for XCD locality
  const int qtile = 15 - (int)blockIdx.y;  // longest blocks dispatch first
  const int b = bh >> 4, h = bh & 15;

  // 32KB flat LDS: [0,8192) = K dbuf, [8192,16384) = V^T dbuf (shorts). Epilogue reuses it.
  __shared__ unsigned short smem[4 * 64 * 64];

  const int tid  = threadIdx.x;
  const int lane = tid & 63;
  const int wid  = tid >> 6;
  const int hi   = lane >> 5;       // half-wave
  const int lo5  = lane & 31;       // this lane's q (and d) row index

  const size_t headoff  = (size_t)b * S_ * D_ + (size_t)h * DK_;
  const size_t vheadoff = (size_t)(h * DK_) * (size_t)(B_ * S_) + (size_t)b * S_;

  const int xk = (lo5 & 7) << 4;    // read-side XOR (row&7 == lo5&7 for rows lo5, lo5+32)

  // stage K tile ([kv][dk], 8KB) + V^T tile ([d][kv], 8KB) into dbuf slot bs.
  auto stage = [&](int kt_, int bs) {
#pragma unroll
    for (int i = 0; i < 2; ++i) {
      const int base_ob = i * 4096 + wid * 1024;
      const int ob  = base_ob + lane * 16;
      const int row = ob >> 7;                          // 128B per row
      const int scb = (ob & 127) ^ ((row & 7) << 4);    // swizzled source column (bytes)
      const unsigned short* gk = &kp[headoff + (size_t)(kt_ * 64 + row) * D_ + (scb >> 1)];
      const unsigned short* gv = &vtp[vheadoff + (size_t)row * (B_ * S_) + kt_ * 64 + (scb >> 1)];
      __builtin_amdgcn_global_load_lds(GPTR(gk), SPTR(&smem[bs * 4096 + (base_ob >> 1)]), 16, 0, 0);
      __builtin_amdgcn_global_load_lds(GPTR(gv), SPTR(&smem[8192 + bs * 4096 + (base_ob >> 1)]), 16, 0, 0);
    }
  };

  const int qw = qtile * 128 + wid * 32;   // wave's first q row
  const int qg = qw + lo5;                 // lane's q row

  // Q B-fragments: aq[t] holds Q[qg][dk=16t+8hi .. +8], pre-scaled by 1/8 (exact)
  short8 aq[4];
#pragma unroll
  for (int t = 0; t < 4; ++t) {
    ushort8 raw = *reinterpret_cast<const ushort8*>(
        &qp[headoff + (size_t)qg * D_ + t * 16 + hi * 8]);
    short8 sv;
#pragma unroll
    for (int j = 0; j < 8; ++j) sv[j] = (short)f2bf(bf2f(raw[j]) * 0.125f);
    aq[t] = sv;
  }

  float mrun = -3.0e38f, lrun = 0.f;
  f32x16 oa0, oa1;   // O^T accum: lane holds O[qg][d = d32*32 + (reg&3)+8*(reg>>2)+4*hi]
#pragma unroll
  for (int r = 0; r < 16; ++r) { oa0[r] = 0.f; oa1[r] = 0.f; }

  const int nkv = 2 * (qtile + 1);
  stage(0, 0);  // prologue: 4 loads in flight

  for (int kt = 0; kt < nkv; ++kt) {
    const int cur = kt & 1;
    __builtin_amdgcn_s_barrier();
    __builtin_amdgcn_sched_barrier(0);
    if (kt < nkv - 1) {
      stage(kt + 1, cur ^ 1);                           // issue next tile -> 8 outstanding
      asm volatile("s_waitcnt vmcnt(4)" ::: "memory");  // tile kt's 4 loads done
    } else {
      asm volatile("s_waitcnt vmcnt(0)" ::: "memory");  // last tile: drain
    }
    __builtin_amdgcn_sched_barrier(0);

    const int kv0 = kt * 64;
    if (kv0 <= qw + 31) {   // not fully masked for this wave
      const unsigned short* Kb = &smem[cur * 4096];
      const unsigned short* Vb = &smem[8192 + cur * 4096];

      // ---- S^T = K · Q^T : st{0,1}[reg] = S[kv0 + s*32 + (reg&3)+8*(reg>>2)+4*hi][qg]
      f32x16 st0, st1;
#pragma unroll
      for (int r = 0; r < 16; ++r) { st0[r] = 0.f; st1[r] = 0.f; }
      __builtin_amdgcn_s_setprio(1);
#pragma unroll
      for (int t = 0; t < 4; ++t) {
        const int off = ((32 * t + 16 * hi) ^ xk) >> 1;   // shorts
        short8 k0 = *reinterpret_cast<const short8*>(&Kb[lo5 * 64 + off]);
        short8 k1 = *reinterpret_cast<const short8*>(&Kb[(32 + lo5) * 64 + off]);
        st0 = __builtin_amdgcn_mfma_f32_32x32x16_bf16(k0, aq[t], st0, 0, 0, 0);
        st1 = __builtin_amdgcn_mfma_f32_32x32x16_bf16(k1, aq[t], st1, 0, 0, 0);
      }
      __builtin_amdgcn_s_setprio(0);

      // ---- causal mask (only when tile overlaps the diagonal for this wave)
      if (kv0 + 63 > qw) {
#pragma unroll
        for (int r = 0; r < 16; ++r) {
          const int kvl = kv0 + (r & 3) + 8 * (r >> 2) + 4 * hi;
          if (kvl > qg)      st0[r] = -3.0e38f;
          if (kvl + 32 > qg) st1[r] = -3.0e38f;
        }
      }

      // ---- row max (in-lane tree + one cross-half exchange) with T13 defer-max
      float tm = fmaxf(st0[0], st1[0]);
#pragma unroll
      for (int r = 1; r < 16; ++r) tm = fmaxf(tm, fmaxf(st0[r], st1[r]));
      tm = fmaxf(tm, __shfl_xor(tm, 32));
      const bool grow = !__all(tm <= mrun + 8.0f);   // wave-uniform
      float alpha = 1.0f;
      if (grow) {
        const float newm = fmaxf(mrun, tm);
        alpha = __expf(mrun - newm);
        mrun = newm;
      }

      // ---- exp + sum + pack subtile 0 (cvt_pk + permlane32_swap, no hi branch)
      float ls = 0.f;
#pragma unroll
      for (int r = 0; r < 16; ++r) { st0[r] = __expf(st0[r] - mrun); ls += st0[r]; }
      uint32_t a0 = pkbf(st0[0],  st0[1]),  a1 = pkbf(st0[2],  st0[3]);
      uint32_t b0 = pkbf(st0[4],  st0[5]),  b1 = pkbf(st0[6],  st0[7]);
      uint32_t c0 = pkbf(st0[8],  st0[9]),  c1 = pkbf(st0[10], st0[11]);
      uint32_t d0 = pkbf(st0[12], st0[13]), d1 = pkbf(st0[14], st0[15]);
      pl32(a0, b0); pl32(a1, b1);
      pl32(c0, d0); pl32(c1, d1);
      short8 pf0 = mk8(a0, a1, b0, b1);   // kv block 0..15
      short8 pf1 = mk8(c0, c1, d0, d1);   // kv block 16..31

      // ---- exp + sum + pack subtile 1
#pragma unroll
      for (int r = 0; r < 16; ++r) { st1[r] = __expf(st1[r] - mrun); ls += st1[r]; }
      uint32_t e0 = pkbf(st1[0],  st1[1]),  e1 = pkbf(st1[2],  st1[3]);
      uint32_t f0 = pkbf(st1[4],  st1[5]),  f1 = pkbf(st1[6],  st1[7]);
      uint32_t g0 = pkbf(st1[8],  st1[9]),  g1 = pkbf(st1[10], st1[11]);
      uint32_t h0 = pkbf(st1[12], st1[13]), h1 = pkbf(st1[14], st1[15]);
      pl32(e0, f0); pl32(e1, f1);
      pl32(g0, h0); pl32(g1, h1);
      short8 pf2 = mk8(e0, e1, f0, f1);   // kv block 32..47
      short8 pf3 = mk8(g0, g1, h0, h1);   // kv block 48..63

      // ---- running sum + (conditional) O rescale
      ls += __shfl_xor(ls, 32);
      if (grow) {
        lrun = lrun * alpha + ls;
#pragma unroll
        for (int r = 0; r < 16; ++r) { oa0[r] *= alpha; oa1[r] *= alpha; }
      } else {
        lrun += ls;
      }

      // ---- O^T += V^T · P^T : A = V^T frag (rows d), B = P frag
      __builtin_amdgcn_s_setprio(1);
#pragma unroll
      for (int c4 = 0; c4 < 4; ++c4) {
        const int off = ((32 * c4 + 16 * hi) ^ xk) >> 1;
        short8 v0 = *reinterpret_cast<const short8*>(&Vb[lo5 * 64 + off]);
        short8 v1 = *reinterpret_cast<const short8*>(&Vb[(32 + lo5) * 64 + off]);
        const short8 pf = (c4 == 0) ? pf0 : (c4 == 1) ? pf1 : (c4 == 2) ? pf2 : pf3;
        oa0 = __builtin_amdgcn_mfma_f32_32x32x16_bf16(v0, pf, oa0, 0, 0, 0);
        oa1 = __builtin_amdgcn_mfma_f32_32x32x16_bf16(v1, pf, oa1, 0, 0, 0);
      }
      __builtin_amdgcn_s_setprio(0);
    }
  }

  // all waves' final-tile LDS reads consumed before epilogue reuses smem
  __builtin_amdgcn_s_barrier();
  __builtin_amdgcn_sched_barrier(0);

  // ---- epilogue: O^T -> LDS (per-wave region, pitch 72) -> coalesced global write
  {
    unsigned short* sO = &smem[wid * (32 * 72)];
    const float inv = 1.0f / lrun;
#pragma unroll
    for (int r = 0; r < 16; ++r) {
      const int dl = (r & 3) + 8 * (r >> 2) + 4 * hi;
      sO[lo5 * 72 + dl]      = f2bf(oa0[r] * inv);
      sO[lo5 * 72 + 32 + dl] = f2bf(oa1[r] * inv);
    }
    asm volatile("s_waitcnt lgkmcnt(0)" ::: "memory");  // own-wave LDS writes visible
    const int row = lane >> 1, h2 = lane & 1;
    const unsigned short* src = &smem[wid * (32 * 72) + row * 72 + h2 * 32];
    unsigned short* dst = &attn[headoff + (size_t)(qtile * 128 + wid * 32 + row) * D_ + h2 * 32];
#pragma unroll
    for (int j = 0; j < 4; ++j)
      *reinterpret_cast<short8*>(dst + 8 * j) = *reinterpret_cast<const short8*>(src + 8 * j);
  }
}

// ---------------- launcher ----------------
extern "C" void kernel_launch(void* const* d_in, const int* in_sizes, int n_in,
                              void* d_out, int out_size, void* d_ws, size_t ws_size,
                              hipStream_t stream) {
  const float* Q  = (const float*)d_in[0];
  const float* K  = (const float*)d_in[1];
  const float* V  = (const float*)d_in[2];
  // d_in[3] = mask: known causal tril, applied analytically
  const float* Wq = (const float*)d_in[4];
  const float* Wk = (const float*)d_in[5];
  const float* Wv = (const float*)d_in[6];
  const float* Wo = (const float*)d_in[7];
  float* out = (float*)d_out;

  const size_t NX = (size_t)B_ * S_ * D_;  // 8,388,608
  const size_t NW = (size_t)D_ * D_;       // 1,048,576

  unsigned short* ws = (unsigned short*)d_ws;
  unsigned short* Wb = ws;                 // 4*NW
  unsigned short* Pj = Wb + 4 * NW;        // 3*NX  (qp, kp, vtp[D][B*S])
  unsigned short* At = Pj + 3 * NX;        // NX

  const int M = B_ * S_;  // 8192
  dim3 blk(256);
  dim3 gridConvW((unsigned)(NW / 4 / 256), 1, 4);
  dim3 gridQKV(512, 1, 3);
  dim3 gridOut(M / BM, D_ / BN);           // m-major: same-panel blocks share an XCD
  dim3 gridAttn(B_ * H_, 16);              // head-major: same-head blocks share an XCD

  // weights -> bf16 (X is read fp32-direct by gemm_qkv)
  conv_w4<<<gridConvW, blk, 0, stream>>>(Wq, Wk, Wv, Wo, Wb);
  // QKV projection (fp32 X staged + converted in-kernel; V written directly transposed)
  gemm_qkv<<<gridQKV, blk, 0, stream>>>(Q, K, V, Wb, Pj);
  // attention (V^T layout [D][B*S])
  attn_fwd<<<gridAttn, blk, 0, stream>>>(Pj, Pj + NX, Pj + 2 * NX, At);
  // output projection (fp32 out)
  gemm_out<<<gridOut, blk, 0, stream>>>(At, Wb + 3 * NW, out, M, D_, D_);
}